// Round 6
// baseline (132.710 us; speedup 1.0000x reference)
//
#include <hip/hip_runtime.h>
#include <hip/hip_bf16.h>

#define ALPHA 0.2f
#define NROW 8192
#define NST  32     // steps per wave; step = 32 j-cols

typedef __attribute__((ext_vector_type(4))) float f4;
typedef __attribute__((ext_vector_type(8))) short s8;

__device__ __forceinline__ short f2bf_bits(float x){
    __hip_bfloat16 b = __float2bfloat16(x);
    return __builtin_bit_cast(short, b);
}

// K1: h = x@W ; s1 ; s2 ; F1=exp(s2) ; F2=exp(0.2*s2) ; hT[f][i] = bf16(h[i][f])
__global__ __launch_bounds__(256) void k_proj(
    const float* __restrict__ x, const float* __restrict__ W, const float* __restrict__ a,
    float* __restrict__ s1, float* __restrict__ s2,
    float* __restrict__ F1, float* __restrict__ F2, __hip_bfloat16* __restrict__ hT)
{
    __shared__ float Wsh[128*64];
    __shared__ float xsh[4*128];
    const int t = threadIdx.x;
    const int f = t & 63, ry = t >> 6;
    const int row0 = blockIdx.x * 4;
    for (int i = t; i < 128*64; i += 256) Wsh[i] = W[i];
    for (int i = t; i < 4*128; i += 256) xsh[i] = x[row0*128 + i];
    __syncthreads();
    float acc = 0.f;
    #pragma unroll
    for (int k = 0; k < 128; ++k) acc = fmaf(xsh[ry*128 + k], Wsh[k*64 + f], acc);
    float p1 = acc * a[f], p2 = acc * a[64 + f];
    #pragma unroll
    for (int m = 32; m; m >>= 1){ p1 += __shfl_xor(p1, m, 64); p2 += __shfl_xor(p2, m, 64); }
    const int row = row0 + ry;
    if (f == 0){
        s1[row] = p1; s2[row] = p2;
        F1[row] = __expf(p2); F2[row] = __expf(0.2f * p2);
    }
    hT[f * NROW + row] = __float2bfloat16(acc);
}

// K2: s2max = max(s2)
__global__ __launch_bounds__(1024) void k_s2max(const float* __restrict__ s2, float* __restrict__ s2max)
{
    __shared__ float red[1024];
    float m = -1e30f;
    for (int i = threadIdx.x; i < NROW; i += 1024) m = fmaxf(m, s2[i]);
    red[threadIdx.x] = m; __syncthreads();
    for (int s = 512; s; s >>= 1){
        if (threadIdx.x < (unsigned)s) red[threadIdx.x] = fmaxf(red[threadIdx.x], red[threadIdx.x + s]);
        __syncthreads();
    }
    if (threadIdx.x == 0) s2max[0] = red[0];
}

// K3: register-only 4-slot rotating pipeline, depth 3, barrier-free.
// Each step = exactly 10 vm-ops (2 adj + 4 h + 4 F); vmcnt(20) keeps 2 steps
// in flight per wave at all times. 256-VGPR cap via __launch_bounds__(512,2).
__global__ __launch_bounds__(512, 2) void k_attn5(
    const float* __restrict__ adj, const float* __restrict__ s1g,
    const float* __restrict__ s2maxp, const float* __restrict__ F1g,
    const float* __restrict__ F2g, const __hip_bfloat16* __restrict__ hT,
    float* __restrict__ out)
{
    __shared__ float accb[8][16][64];   // 32 KB (epilogue only)
    __shared__ float lsb[8][16];

    const int tid = threadIdx.x;
    const int w = tid >> 6, lane = tid & 63;
    const int lr = lane & 15, hi = lane >> 4;
    const int i0 = blockIdx.x * 16, row = i0 + lr;

    const float s1r = s1g[row];
    const float t0 = s1r + s2maxp[0];
    const float Mr = fmaxf(t0, ALPHA * t0);      // >= true row max of lrelu logits
    const float E1 = __expf(s1r - Mr);           // t>0:  p = E1*F1_j
    const float E2 = __expf(ALPHA * s1r - Mr);   // t<=0: p = E2*F2_j
    const float T1 = __expf(-s1r);               // (t>0) <=> F1_j > T1

    const int jw = w * 1024;
    const float* adjp = adj + (long)row * NROW + jw + hi * 8;
    const __hip_bfloat16* hq0 = hT + lr * NROW + jw + hi * 8;
    const float* f1p = F1g + jw + hi * 8;
    const float* f2p = F2g + jw + hi * 8;

    f4 acc0 = {0.f,0.f,0.f,0.f}, acc1 = {0.f,0.f,0.f,0.f};
    f4 acc2 = {0.f,0.f,0.f,0.f}, acc3 = {0.f,0.f,0.f,0.f};
    float lsum = 0.f;

#define DECL_SLOT(S) s8 h0##S,h1##S,h2##S,h3##S; f4 f1a##S,f1b##S,f2a##S,f2b##S,a0##S,a1##S;
    DECL_SLOT(S0) DECL_SLOT(S1) DECL_SLOT(S2) DECL_SLOT(S3)
#undef DECL_SLOT

// exactly 10 vm-ops, issued in one contiguous block
#define LOAD(S, s) do { \
    const float* ap = adjp + (s) * 32; \
    a0##S = *(const f4*)(ap);  a1##S = *(const f4*)(ap + 4); \
    const __hip_bfloat16* hq = hq0 + (s) * 32; \
    h0##S = *(const s8*)(hq); \
    h1##S = *(const s8*)(hq + 16 * NROW); \
    h2##S = *(const s8*)(hq + 32 * NROW); \
    h3##S = *(const s8*)(hq + 48 * NROW); \
    const float* f1_ = f1p + (s) * 32; \
    const float* f2_ = f2p + (s) * 32; \
    f1a##S = *(const f4*)(f1_); f1b##S = *(const f4*)(f1_ + 4); \
    f2a##S = *(const f4*)(f2_); f2b##S = *(const f4*)(f2_ + 4); \
} while(0)

#define CALCQ(av, g1, g2, qd) { \
    float fz = ((g1) > T1) ? (g1) * E1 : (g2) * E2; \
    qd = ((av) > 0.f) ? fz : 0.f; }

#define STEP(S) do { \
    float q0,q1,q2,q3,q4,q5,q6,q7; \
    CALCQ(a0##S[0], f1a##S[0], f2a##S[0], q0); CALCQ(a0##S[1], f1a##S[1], f2a##S[1], q1); \
    CALCQ(a0##S[2], f1a##S[2], f2a##S[2], q2); CALCQ(a0##S[3], f1a##S[3], f2a##S[3], q3); \
    CALCQ(a1##S[0], f1b##S[0], f2b##S[0], q4); CALCQ(a1##S[1], f1b##S[1], f2b##S[1], q5); \
    CALCQ(a1##S[2], f1b##S[2], f2b##S[2], q6); CALCQ(a1##S[3], f1b##S[3], f2b##S[3], q7); \
    lsum += ((q0+q1)+(q2+q3)) + ((q4+q5)+(q6+q7)); \
    s8 af; \
    af[0]=f2bf_bits(q0); af[1]=f2bf_bits(q1); af[2]=f2bf_bits(q2); af[3]=f2bf_bits(q3); \
    af[4]=f2bf_bits(q4); af[5]=f2bf_bits(q5); af[6]=f2bf_bits(q6); af[7]=f2bf_bits(q7); \
    acc0 = __builtin_amdgcn_mfma_f32_16x16x32_bf16(af, h0##S, acc0, 0, 0, 0); \
    acc1 = __builtin_amdgcn_mfma_f32_16x16x32_bf16(af, h1##S, acc1, 0, 0, 0); \
    acc2 = __builtin_amdgcn_mfma_f32_16x16x32_bf16(af, h2##S, acc2, 0, 0, 0); \
    acc3 = __builtin_amdgcn_mfma_f32_16x16x32_bf16(af, h3##S, acc3, 0, 0, 0); \
} while(0)

#define WAIT20 asm volatile("s_waitcnt vmcnt(20)" ::: "memory")

    LOAD(S0, 0); LOAD(S1, 1); LOAD(S2, 2);

    for (int sb = 0; sb < 28; sb += 4){
        WAIT20; STEP(S0); LOAD(S3, sb + 3);
        WAIT20; STEP(S1); LOAD(S0, sb + 4);
        WAIT20; STEP(S2); LOAD(S1, sb + 5);
        WAIT20; STEP(S3); LOAD(S2, sb + 6);
    }
    // steps 28..31 live in S0,S1,S2 (+31 loaded now into S3)
    WAIT20; STEP(S0); LOAD(S3, 31);
    WAIT20; STEP(S1);
    asm volatile("s_waitcnt vmcnt(10)" ::: "memory");
    STEP(S2);
    asm volatile("s_waitcnt vmcnt(0)" ::: "memory");
    STEP(S3);

#undef LOAD
#undef CALCQ
#undef STEP
#undef WAIT20

    lsum += __shfl_xor(lsum, 16, 64);
    lsum += __shfl_xor(lsum, 32, 64);

    // C layout: col = lane&15, row = (lane>>4)*4 + reg
    #pragma unroll
    for (int r = 0; r < 4; ++r){
        accb[w][hi*4 + r][ 0 + lr] = acc0[r];
        accb[w][hi*4 + r][16 + lr] = acc1[r];
        accb[w][hi*4 + r][32 + lr] = acc2[r];
        accb[w][hi*4 + r][48 + lr] = acc3[r];
    }
    if (lane < 16) lsb[w][lane] = lsum;
    __syncthreads();

    for (int idx = tid; idx < 1024; idx += 512){
        int r = idx >> 6, cf = idx & 63;
        float sa = 0.f, L = 0.f;
        #pragma unroll
        for (int ww = 0; ww < 8; ++ww){ sa += accb[ww][r][cf]; L += lsb[ww][r]; }
        float v = sa / L;
        out[(long)(i0 + r) * 64 + cf] = (v > 0.f) ? v : expm1f(v);
    }
}

extern "C" void kernel_launch(void* const* d_in, const int* in_sizes, int n_in,
                              void* d_out, int out_size, void* d_ws, size_t ws_size,
                              hipStream_t stream)
{
    const float* x   = (const float*)d_in[0];
    const float* adj = (const float*)d_in[1];
    const float* W   = (const float*)d_in[2];
    const float* a   = (const float*)d_in[3];
    float* out = (float*)d_out;

    char* ws = (char*)d_ws;
    float* s1   = (float*)(ws);                    // 32 KB
    float* s2   = (float*)(ws + 32768);            // 32 KB
    float* F1   = (float*)(ws + 65536);            // 32 KB
    float* F2   = (float*)(ws + 98304);            // 32 KB
    float* s2mx = (float*)(ws + 131072);           // 256 B
    __hip_bfloat16* hT = (__hip_bfloat16*)(ws + 131328);   // 1 MB

    k_proj <<<2048,  256, 0, stream>>>(x, W, a, s1, s2, F1, F2, hT);
    k_s2max<<<   1, 1024, 0, stream>>>(s2, s2mx);
    k_attn5<<< 512,  512, 0, stream>>>(adj, s1, s2mx, F1, F2, hT, out);
}

// Round 7
// 102.782 us; speedup vs baseline: 1.2912x; 1.2912x over previous
//
#include <hip/hip_runtime.h>
#include <hip/hip_bf16.h>

#define ALPHA 0.2f
#define NROW 8192

typedef __attribute__((ext_vector_type(4))) float f4;
typedef __attribute__((ext_vector_type(8))) short s8;

__device__ __forceinline__ short f2bf_bits(float x){
    __hip_bfloat16 b = __float2bfloat16(x);
    return __builtin_bit_cast(short, b);
}

// K1: h = x@W ; s1 ; s2 ; F1=exp(s2) ; F2=exp(0.2*s2) ;
// hpack = h in MFMA B-fragment order: element ((s*4+fg)*64 + hi*16 + lr)*8 + e
//   = h[j = s*32 + hi*8 + e][f = fg*16 + lr]  (bf16)
__global__ __launch_bounds__(256) void k_proj(
    const float* __restrict__ x, const float* __restrict__ W, const float* __restrict__ a,
    float* __restrict__ s1, float* __restrict__ s2,
    float* __restrict__ F1, float* __restrict__ F2, __hip_bfloat16* __restrict__ hpack)
{
    __shared__ float Wsh[128*64];
    __shared__ float xsh[4*128];
    const int t = threadIdx.x;
    const int f = t & 63, ry = t >> 6;
    const int row0 = blockIdx.x * 4;
    for (int i = t; i < 128*64; i += 256) Wsh[i] = W[i];
    for (int i = t; i < 4*128; i += 256) xsh[i] = x[row0*128 + i];
    __syncthreads();
    float acc = 0.f;
    #pragma unroll
    for (int k = 0; k < 128; ++k) acc = fmaf(xsh[ry*128 + k], Wsh[k*64 + f], acc);
    float p1 = acc * a[f], p2 = acc * a[64 + f];
    #pragma unroll
    for (int m = 32; m; m >>= 1){ p1 += __shfl_xor(p1, m, 64); p2 += __shfl_xor(p2, m, 64); }
    const int j = row0 + ry;
    if (f == 0){
        s1[j] = p1; s2[j] = p2;
        F1[j] = __expf(p2); F2[j] = __expf(0.2f * p2);
    }
    const int sc = j >> 5, hg = (j >> 3) & 3, e = j & 7;
    const int fg = f >> 4, lr = f & 15;
    hpack[(((sc*4 + fg)*64) + hg*16 + lr)*8 + e] = __float2bfloat16(acc);
}

// K2: s2max = max(s2)
__global__ __launch_bounds__(1024) void k_s2max(const float* __restrict__ s2, float* __restrict__ s2max)
{
    __shared__ float red[1024];
    float m = -1e30f;
    for (int i = threadIdx.x; i < NROW; i += 1024) m = fmaxf(m, s2[i]);
    red[threadIdx.x] = m; __syncthreads();
    for (int s = 512; s; s >>= 1){
        if (threadIdx.x < (unsigned)s) red[threadIdx.x] = fmaxf(red[threadIdx.x], red[threadIdx.x + s]);
        __syncthreads();
    }
    if (threadIdx.x == 0) s2max[0] = red[0];
}

// K3: phase A: coalesced adj stream -> bitmask in LDS (padded, conflict-free).
//     phase B: mask (LDS) + fragment-packed h (L2) + F (L2); MFMA; no barriers.
__global__ __launch_bounds__(512, 4) void k_attn6(
    const float* __restrict__ adj, const float* __restrict__ s1g,
    const float* __restrict__ s2maxp, const float* __restrict__ F1g,
    const float* __restrict__ F2g, const __hip_bfloat16* __restrict__ hpack,
    float* __restrict__ out)
{
    __shared__ __attribute__((aligned(16))) char arena[33280];
    unsigned* maskL = (unsigned*)arena;          // [16][257] u32 = 16448 B (phases A,B)

    const int tid = threadIdx.x;
    const int w = tid >> 6, lane = tid & 63;
    const int lr = lane & 15, hi = lane >> 4;
    const int i0 = blockIdx.x * 16, row = i0 + lr;

    // ---- phase A: adj -> bitmask (each lane: contiguous 128B chunks of one row)
    {
        const int rloc = 2*w + (lane >> 5);
        const int sl = lane & 31;
        const float* arow = adj + (long)(i0 + rloc) * NROW;
        #pragma unroll 2
        for (int it = 0; it < 8; ++it){
            const int s = it*32 + sl;
            const float* p = arow + s*32;
            f4 v0 = *(const f4*)(p);      f4 v1 = *(const f4*)(p + 4);
            f4 v2 = *(const f4*)(p + 8);  f4 v3 = *(const f4*)(p + 12);
            f4 v4 = *(const f4*)(p + 16); f4 v5 = *(const f4*)(p + 20);
            f4 v6 = *(const f4*)(p + 24); f4 v7 = *(const f4*)(p + 28);
            unsigned m = 0;
            #pragma unroll
            for (int e = 0; e < 4; ++e){
                m |= (v0[e] > 0.f) ? (1u << ( 0 + e)) : 0u;
                m |= (v1[e] > 0.f) ? (1u << ( 4 + e)) : 0u;
                m |= (v2[e] > 0.f) ? (1u << ( 8 + e)) : 0u;
                m |= (v3[e] > 0.f) ? (1u << (12 + e)) : 0u;
                m |= (v4[e] > 0.f) ? (1u << (16 + e)) : 0u;
                m |= (v5[e] > 0.f) ? (1u << (20 + e)) : 0u;
                m |= (v6[e] > 0.f) ? (1u << (24 + e)) : 0u;
                m |= (v7[e] > 0.f) ? (1u << (28 + e)) : 0u;
            }
            maskL[rloc*257 + s] = m;
        }
    }
    __syncthreads();

    // ---- phase B
    const float s1r = s1g[row];
    const float t0 = s1r + s2maxp[0];
    const float Mr = fmaxf(t0, ALPHA * t0);      // >= true row max of lrelu logits
    const float E1 = __expf(s1r - Mr);           // t>0:  p = E1*F1_j
    const float E2 = __expf(ALPHA * s1r - Mr);   // t<=0: p = E2*F2_j
    const float T1 = __expf(-s1r);               // (t>0) <=> F1_j > T1

    const int s0 = w * 32;
    const s8* hpb = (const s8*)hpack + s0*4*64 + lane;   // + t*256 + fg*64
    const float* f1p = F1g + s0*32 + hi*8;
    const float* f2p = F2g + s0*32 + hi*8;
    const int mofs = lr*257 + s0;

    f4 acc0 = {0.f,0.f,0.f,0.f}, acc1 = {0.f,0.f,0.f,0.f};
    f4 acc2 = {0.f,0.f,0.f,0.f}, acc3 = {0.f,0.f,0.f,0.f};
    float lsum = 0.f;

    unsigned mwA, mwB;
    s8 h0A,h1A,h2A,h3A, h0B,h1B,h2B,h3B;
    f4 f1aA,f1bA,f2aA,f2bA, f1aB,f1bB,f2aB,f2bB;

#define LOADALL(S, t) do { \
    mw##S = maskL[mofs + (t)]; \
    h0##S = hpb[(t)*256];       h1##S = hpb[(t)*256 + 64]; \
    h2##S = hpb[(t)*256 + 128]; h3##S = hpb[(t)*256 + 192]; \
    const float* f1_ = f1p + (t)*32; \
    const float* f2_ = f2p + (t)*32; \
    f1a##S = *(const f4*)(f1_); f1b##S = *(const f4*)(f1_ + 4); \
    f2a##S = *(const f4*)(f2_); f2b##S = *(const f4*)(f2_ + 4); \
} while(0)

#define CALCQ(bc, g1, g2, qd) { \
    float fz = ((g1) > T1) ? (g1) * E1 : (g2) * E2; \
    qd = (mb & (bc)) ? fz : 0.f; }

#define STEP(S) do { \
    unsigned mb = mw##S >> (hi*8); \
    float q0,q1,q2,q3,q4,q5,q6,q7; \
    CALCQ(1u,   f1a##S[0], f2a##S[0], q0); CALCQ(2u,   f1a##S[1], f2a##S[1], q1); \
    CALCQ(4u,   f1a##S[2], f2a##S[2], q2); CALCQ(8u,   f1a##S[3], f2a##S[3], q3); \
    CALCQ(16u,  f1b##S[0], f2b##S[0], q4); CALCQ(32u,  f1b##S[1], f2b##S[1], q5); \
    CALCQ(64u,  f1b##S[2], f2b##S[2], q6); CALCQ(128u, f1b##S[3], f2b##S[3], q7); \
    lsum += ((q0+q1)+(q2+q3)) + ((q4+q5)+(q6+q7)); \
    s8 af; \
    af[0]=f2bf_bits(q0); af[1]=f2bf_bits(q1); af[2]=f2bf_bits(q2); af[3]=f2bf_bits(q3); \
    af[4]=f2bf_bits(q4); af[5]=f2bf_bits(q5); af[6]=f2bf_bits(q6); af[7]=f2bf_bits(q7); \
    acc0 = __builtin_amdgcn_mfma_f32_16x16x32_bf16(af, h0##S, acc0, 0, 0, 0); \
    acc1 = __builtin_amdgcn_mfma_f32_16x16x32_bf16(af, h1##S, acc1, 0, 0, 0); \
    acc2 = __builtin_amdgcn_mfma_f32_16x16x32_bf16(af, h2##S, acc2, 0, 0, 0); \
    acc3 = __builtin_amdgcn_mfma_f32_16x16x32_bf16(af, h3##S, acc3, 0, 0, 0); \
} while(0)

    LOADALL(A, 0);
    for (int t = 0; t < 32; t += 2){
        LOADALL(B, t + 1);
        STEP(A);
        if (t + 2 < 32) LOADALL(A, t + 2);
        STEP(B);
    }
#undef LOADALL
#undef CALCQ
#undef STEP

    lsum += __shfl_xor(lsum, 16, 64);
    lsum += __shfl_xor(lsum, 32, 64);

    __syncthreads();   // all waves done with maskL -> reuse arena for epilogue
    float* accb = (float*)arena;               // [8][16][64] = 32 KB
    float* lsb  = (float*)(arena + 32768);     // [8][16]

    // C layout: col = lane&15, row = (lane>>4)*4 + reg
    #pragma unroll
    for (int r = 0; r < 4; ++r){
        accb[((w*16 + hi*4 + r) << 6) +  0 + lr] = acc0[r];
        accb[((w*16 + hi*4 + r) << 6) + 16 + lr] = acc1[r];
        accb[((w*16 + hi*4 + r) << 6) + 32 + lr] = acc2[r];
        accb[((w*16 + hi*4 + r) << 6) + 48 + lr] = acc3[r];
    }
    if (lane < 16) lsb[w*16 + lane] = lsum;
    __syncthreads();

    for (int idx = tid; idx < 1024; idx += 512){
        int r = idx >> 6, cf = idx & 63;
        float sa = 0.f, L = 0.f;
        #pragma unroll
        for (int ww = 0; ww < 8; ++ww){ sa += accb[((ww*16 + r) << 6) + cf]; L += lsb[ww*16 + r]; }
        float v = sa / L;
        out[(long)(i0 + r) * 64 + cf] = (v > 0.f) ? v : expm1f(v);
    }
}

extern "C" void kernel_launch(void* const* d_in, const int* in_sizes, int n_in,
                              void* d_out, int out_size, void* d_ws, size_t ws_size,
                              hipStream_t stream)
{
    const float* x   = (const float*)d_in[0];
    const float* adj = (const float*)d_in[1];
    const float* W   = (const float*)d_in[2];
    const float* a   = (const float*)d_in[3];
    float* out = (float*)d_out;

    char* ws = (char*)d_ws;
    float* s1   = (float*)(ws);                    // 32 KB
    float* s2   = (float*)(ws + 32768);            // 32 KB
    float* F1   = (float*)(ws + 65536);            // 32 KB
    float* F2   = (float*)(ws + 98304);            // 32 KB
    float* s2mx = (float*)(ws + 131072);           // 256 B
    __hip_bfloat16* hpack = (__hip_bfloat16*)(ws + 131328);   // 1 MB

    k_proj <<<2048,  256, 0, stream>>>(x, W, a, s1, s2, F1, F2, hpack);
    k_s2max<<<   1, 1024, 0, stream>>>(s2, s2mx);
    k_attn6<<< 512,  512, 0, stream>>>(adj, s1, s2mx, F1, F2, hpack, out);
}

// Round 8
// 98.556 us; speedup vs baseline: 1.3465x; 1.0429x over previous
//
#include <hip/hip_runtime.h>
#include <hip/hip_bf16.h>

#define ALPHA 0.2f
#define NROW 8192

typedef __attribute__((ext_vector_type(4))) float f4;
typedef __attribute__((ext_vector_type(8))) short s8;
typedef __attribute__((ext_vector_type(4))) unsigned u4;

__device__ __forceinline__ short f2bf_bits(float x){
    __hip_bfloat16 b = __float2bfloat16(x);
    return __builtin_bit_cast(short, b);
}

// K1: h = x@W ; s1 ; s2 ; F1=exp(s2) ; F2=exp(0.2*s2) ;
// hpack = h in MFMA B-fragment order: element ((sc*4+fg)*64 + hg*16 + lr)*8 + e
//   = h[j = sc*32 + hg*8 + e][f = fg*16 + lr]  (bf16)
__global__ __launch_bounds__(256) void k_proj(
    const float* __restrict__ x, const float* __restrict__ W, const float* __restrict__ a,
    float* __restrict__ s1, float* __restrict__ s2,
    float* __restrict__ F1, float* __restrict__ F2, __hip_bfloat16* __restrict__ hpack)
{
    __shared__ float Wsh[128*64];
    __shared__ float xsh[4*128];
    const int t = threadIdx.x;
    const int f = t & 63, ry = t >> 6;
    const int row0 = blockIdx.x * 4;
    for (int i = t; i < 128*64; i += 256) Wsh[i] = W[i];
    for (int i = t; i < 4*128; i += 256) xsh[i] = x[row0*128 + i];
    __syncthreads();
    float acc = 0.f;
    #pragma unroll
    for (int k = 0; k < 128; ++k) acc = fmaf(xsh[ry*128 + k], Wsh[k*64 + f], acc);
    float p1 = acc * a[f], p2 = acc * a[64 + f];
    #pragma unroll
    for (int m = 32; m; m >>= 1){ p1 += __shfl_xor(p1, m, 64); p2 += __shfl_xor(p2, m, 64); }
    const int j = row0 + ry;
    if (f == 0){
        s1[j] = p1; s2[j] = p2;
        F1[j] = __expf(p2); F2[j] = __expf(0.2f * p2);
    }
    const int sc = j >> 5, hg = (j >> 3) & 3, e = j & 7;
    const int fg = f >> 4, lr = f & 15;
    hpack[(((sc*4 + fg)*64) + hg*16 + lr)*8 + e] = __float2bfloat16(acc);
}

// K2: s2max = max(s2)
__global__ __launch_bounds__(1024) void k_s2max(const float* __restrict__ s2, float* __restrict__ s2max)
{
    __shared__ float red[1024];
    float m = -1e30f;
    for (int i = threadIdx.x; i < NROW; i += 1024) m = fmaxf(m, s2[i]);
    red[threadIdx.x] = m; __syncthreads();
    for (int s = 512; s; s >>= 1){
        if (threadIdx.x < (unsigned)s) red[threadIdx.x] = fmaxf(red[threadIdx.x], red[threadIdx.x + s]);
        __syncthreads();
    }
    if (threadIdx.x == 0) s2max[0] = red[0];
}

// K3: phase A: fully-coalesced adj stream -> ballot bitmask in LDS.
//   mask layout: [chunk(256 cols)][row][32B] ; 32B = {lo32(b0..b3), hi32(b0..b3)}
//   ballot e bit l  <=>  col (chunk*256 + 4*l + e) > 0
// phase B: mask (LDS broadcast) + fragment-packed h (L2) + F (L2); MFMA; no barriers.
__global__ __launch_bounds__(512, 4) void k_attn7(
    const float* __restrict__ adj, const float* __restrict__ s1g,
    const float* __restrict__ s2maxp, const float* __restrict__ F1g,
    const float* __restrict__ F2g, const __hip_bfloat16* __restrict__ hpack,
    float* __restrict__ out)
{
    __shared__ __attribute__((aligned(16))) char arena[33280];
    char* maskB = arena;                       // 32 chunks x 16 rows x 32 B = 16 KB

    const int tid = threadIdx.x;
    const int w = tid >> 6, lane = tid & 63;
    const int lr = lane & 15, hi = lane >> 4;
    const int i0 = blockIdx.x * 16, row = i0 + lr;

    // ---- phase A: ballot-compress (lane l reads 16 B at base + l*16: perfect coalescing)
    {
        const int r0 = 2 * w;
        #pragma unroll
        for (int rr = 0; rr < 2; ++rr){
            const float* arow = adj + (long)(i0 + r0 + rr) * NROW + lane * 4;
            char* mret = maskB + (r0 + rr) * 32;
#define BSTORE(v, c) do { \
            unsigned long long b0 = __ballot((v)[0] > 0.f); \
            unsigned long long b1 = __ballot((v)[1] > 0.f); \
            unsigned long long b2 = __ballot((v)[2] > 0.f); \
            unsigned long long b3 = __ballot((v)[3] > 0.f); \
            if (lane == 0){ \
                u4* dst = (u4*)(mret + (c) * 512); \
                dst[0] = (u4){(unsigned)b0, (unsigned)b1, (unsigned)b2, (unsigned)b3}; \
                dst[1] = (u4){(unsigned)(b0>>32), (unsigned)(b1>>32), (unsigned)(b2>>32), (unsigned)(b3>>32)}; \
            } } while(0)
            for (int c = 0; c < 32; c += 4){
                f4 v0 = *(const f4*)(arow + (c    )*256);
                f4 v1 = *(const f4*)(arow + (c + 1)*256);
                f4 v2 = *(const f4*)(arow + (c + 2)*256);
                f4 v3 = *(const f4*)(arow + (c + 3)*256);
                BSTORE(v0, c); BSTORE(v1, c + 1); BSTORE(v2, c + 2); BSTORE(v3, c + 3);
            }
#undef BSTORE
        }
    }
    __syncthreads();

    // ---- phase B
    const float s1r = s1g[row];
    const float t0 = s1r + s2maxp[0];
    const float Mr = fmaxf(t0, ALPHA * t0);      // >= true row max of lrelu logits
    const float E1 = __expf(s1r - Mr);           // t>0:  p = E1*F1_j
    const float E2 = __expf(ALPHA * s1r - Mr);   // t<=0: p = E2*F2_j
    const float T1 = __expf(-s1r);               // (t>0) <=> F1_j > T1

    const int s0 = w * 32;
    const s8* hpb = (const s8*)hpack + s0*4*64 + lane;   // + t*256 + fg*64
    const float* f1p = F1g + s0*32 + hi*8;
    const float* f2p = F2g + s0*32 + hi*8;
    const char* mrow = maskB + (w*4)*512 + lr*32;        // + (t>>3)*512 + ((t>>2)&1)*16
    const int hi2 = hi * 2;

    f4 acc0 = {0.f,0.f,0.f,0.f}, acc1 = {0.f,0.f,0.f,0.f};
    f4 acc2 = {0.f,0.f,0.f,0.f}, acc3 = {0.f,0.f,0.f,0.f};
    float lsum = 0.f;

    u4 mqA, mqB;
    s8 h0A,h1A,h2A,h3A, h0B,h1B,h2B,h3B;

#define LOADALL(S, t) do { \
    mq##S = *(const u4*)(mrow + ((t)>>3)*512 + (((t)>>2)&1)*16); \
    h0##S = hpb[(t)*256];       h1##S = hpb[(t)*256 + 64]; \
    h2##S = hpb[(t)*256 + 128]; h3##S = hpb[(t)*256 + 192]; \
} while(0)

#define CALCQ(cond, g1, g2, qd) { \
    float fz = ((g1) > T1) ? (g1) * E1 : (g2) * E2; \
    qd = (cond) ? fz : 0.f; }

#define STEP(S, t) do { \
    const float* f1_ = f1p + (t)*32; \
    const float* f2_ = f2p + (t)*32; \
    f4 f1a = *(const f4*)(f1_); f4 f1b = *(const f4*)(f1_ + 4); \
    f4 f2a = *(const f4*)(f2_); f4 f2b = *(const f4*)(f2_ + 4); \
    const unsigned sh = ((t)&3)*8 + hi2; \
    const unsigned b0 = mq##S[0] >> sh, b1 = mq##S[1] >> sh; \
    const unsigned b2 = mq##S[2] >> sh, b3 = mq##S[3] >> sh; \
    float q0,q1,q2,q3,q4,q5,q6,q7; \
    CALCQ(b0 & 1u, f1a[0], f2a[0], q0); CALCQ(b1 & 1u, f1a[1], f2a[1], q1); \
    CALCQ(b2 & 1u, f1a[2], f2a[2], q2); CALCQ(b3 & 1u, f1a[3], f2a[3], q3); \
    CALCQ(b0 & 2u, f1b[0], f2b[0], q4); CALCQ(b1 & 2u, f1b[1], f2b[1], q5); \
    CALCQ(b2 & 2u, f1b[2], f2b[2], q6); CALCQ(b3 & 2u, f1b[3], f2b[3], q7); \
    lsum += ((q0+q1)+(q2+q3)) + ((q4+q5)+(q6+q7)); \
    s8 af; \
    af[0]=f2bf_bits(q0); af[1]=f2bf_bits(q1); af[2]=f2bf_bits(q2); af[3]=f2bf_bits(q3); \
    af[4]=f2bf_bits(q4); af[5]=f2bf_bits(q5); af[6]=f2bf_bits(q6); af[7]=f2bf_bits(q7); \
    acc0 = __builtin_amdgcn_mfma_f32_16x16x32_bf16(af, h0##S, acc0, 0, 0, 0); \
    acc1 = __builtin_amdgcn_mfma_f32_16x16x32_bf16(af, h1##S, acc1, 0, 0, 0); \
    acc2 = __builtin_amdgcn_mfma_f32_16x16x32_bf16(af, h2##S, acc2, 0, 0, 0); \
    acc3 = __builtin_amdgcn_mfma_f32_16x16x32_bf16(af, h3##S, acc3, 0, 0, 0); \
} while(0)

    LOADALL(A, 0);
    for (int t = 0; t < 32; t += 2){
        LOADALL(B, t + 1);
        STEP(A, t);
        if (t + 2 < 32) LOADALL(A, t + 2);
        STEP(B, t + 1);
    }
#undef LOADALL
#undef CALCQ
#undef STEP

    lsum += __shfl_xor(lsum, 16, 64);
    lsum += __shfl_xor(lsum, 32, 64);

    __syncthreads();   // done with maskB -> reuse arena for epilogue
    float* accb = (float*)arena;               // [8][16][64] = 32 KB
    float* lsb  = (float*)(arena + 32768);     // [8][16]

    // C layout: col = lane&15, row = (lane>>4)*4 + reg
    #pragma unroll
    for (int r = 0; r < 4; ++r){
        accb[((w*16 + hi*4 + r) << 6) +  0 + lr] = acc0[r];
        accb[((w*16 + hi*4 + r) << 6) + 16 + lr] = acc1[r];
        accb[((w*16 + hi*4 + r) << 6) + 32 + lr] = acc2[r];
        accb[((w*16 + hi*4 + r) << 6) + 48 + lr] = acc3[r];
    }
    if (lane < 16) lsb[w*16 + lane] = lsum;
    __syncthreads();

    for (int idx = tid; idx < 1024; idx += 512){
        int r = idx >> 6, cf = idx & 63;
        float sa = 0.f, L = 0.f;
        #pragma unroll
        for (int ww = 0; ww < 8; ++ww){ sa += accb[((ww*16 + r) << 6) + cf]; L += lsb[ww*16 + r]; }
        float v = sa / L;
        out[(long)(i0 + r) * 64 + cf] = (v > 0.f) ? v : expm1f(v);
    }
}

extern "C" void kernel_launch(void* const* d_in, const int* in_sizes, int n_in,
                              void* d_out, int out_size, void* d_ws, size_t ws_size,
                              hipStream_t stream)
{
    const float* x   = (const float*)d_in[0];
    const float* adj = (const float*)d_in[1];
    const float* W   = (const float*)d_in[2];
    const float* a   = (const float*)d_in[3];
    float* out = (float*)d_out;

    char* ws = (char*)d_ws;
    float* s1   = (float*)(ws);                    // 32 KB
    float* s2   = (float*)(ws + 32768);            // 32 KB
    float* F1   = (float*)(ws + 65536);            // 32 KB
    float* F2   = (float*)(ws + 98304);            // 32 KB
    float* s2mx = (float*)(ws + 131072);           // 256 B
    __hip_bfloat16* hpack = (__hip_bfloat16*)(ws + 131328);   // 1 MB

    k_proj <<<2048,  256, 0, stream>>>(x, W, a, s1, s2, F1, F2, hpack);
    k_s2max<<<   1, 1024, 0, stream>>>(s2, s2mx);
    k_attn7<<< 512,  512, 0, stream>>>(adj, s1, s2mx, F1, F2, hpack, out);
}